// Round 2
// baseline (7227.319 us; speedup 1.0000x reference)
//
#include <hip/hip_runtime.h>

// ResidualVectorQuantizer: N=131072, DIM=128, LEVELS=3, K=1024, BETA=0.25, USAGE_REG=1e-3
// Outputs (flat fp32 in d_out): quantized [N*128] | codes [N*3] | commit | usage
//
// Numerics contract with the np fp32 reference (validated in rounds 2-4 — do not change):
//  - m = x·W_k: strict sequential fmaf chain over k=0..127, single accumulator.
//  - d = (S - 2*m) + w via __fsub_rn/__fmul_rn/__fadd_rn (no contraction).
//  - argmin: first occurrence on ties (lexicographic (value, index) min).
//  - residual chain (x - q0) - q1 elementwise fp32, recomputed from codes per level.
//  - losses: tolerance loose (~2%); commit = sum of d at argmin; avgp fp32; KL f64.
//
// Round 7 post-mortem of round 6: launch_bounds(256,4) set a 64-VGPR budget
// (trace VGPR_Count=64, not the expected 128) -> RA scratch-spilled the ~110-reg
// ping-pong live set in the hot loop: WRITE_SIZE 133 MB -> 7.05 GB, FETCH 40 ->
// 321 MB, 2.6x regression. The ping-pong ITSELF is correct (passed, absmax
// unchanged) and occupancy did rise to 46% -- only the register budget was wrong.
// Fix: amdgpu_waves_per_eu(4) = the direct knob -> 512/4 = 128-VGPR cap. Live set
// acc(64) + bufA(16) + bufB(16) + addressing(~14) ~ 110 fits with zero spill.
// Spill check for the post-mortem: WRITE_SIZE must return to ~133 MB (atomics).

#define NROWS   131072
#define DIMS    128
#define KCODES  1024
#define NLEV    3

#define QF_OFF   ((size_t)NROWS * DIMS)          // 16777216
#define CODE_OFF QF_OFF
#define SCAL_OFF (QF_OFF + (size_t)NROWS * 3)    // 17170432

// ---------------- ws layout ----------------
// avgp   : 3*1024 floats  @ 0        (12288 B)
// commit : 3 doubles      @ 12288    (24 B)
// wk     : 3*1024 floats  @ 12320    (12288 B)
// WT     : 3*128*1024 fl  @ 24608    (1572864 B)  k-major codebooks
#define WS_COMMIT_OFF 12288
#define WS_WK_OFF     12320
#define WS_WT_OFF     24608

__global__ __launch_bounds__(256) void init_acc(float* avgp, double* commit) {
    for (int i = threadIdx.x; i < 3072; i += 256) avgp[i] = 0.0f;
    if (threadIdx.x < 3) commit[threadIdx.x] = 0.0;
}

__global__ __launch_bounds__(256) void wnorm_kernel(const float* __restrict__ W,
                                                    float* __restrict__ wk) {
    const int wave = threadIdx.x >> 6, lane = threadIdx.x & 63;
    const int c = blockIdx.x * 4 + wave;          // 0..3071 (level*1024 + k)
    const float2 v = *(const float2*)(W + (size_t)c * DIMS + 2 * lane);
    float s = v.x * v.x + v.y * v.y;
#pragma unroll
    for (int m = 32; m >= 1; m >>= 1) s += __shfl_xor(s, m, 64);
    if (lane == 0) wk[c] = s;
}

// WT[l][k][c] = W[l][c][k]
__global__ __launch_bounds__(256) void transpose_w(const float* __restrict__ W,
                                                   float* __restrict__ WT) {
    __shared__ float tile[32][65];
    const int l = blockIdx.z, k0 = blockIdx.y * 32, c0 = blockIdx.x * 64;
    const float* Wl = W + (size_t)l * KCODES * DIMS;
    float* WTl = WT + (size_t)l * DIMS * KCODES;
    {
        const int ci = threadIdx.x >> 2;            // 0..63
        const int kg = (threadIdx.x & 3) * 8;       // 0,8,16,24
        const float4 a = *(const float4*)(Wl + (size_t)(c0 + ci) * DIMS + k0 + kg);
        const float4 b = *(const float4*)(Wl + (size_t)(c0 + ci) * DIMS + k0 + kg + 4);
        tile[kg + 0][ci] = a.x; tile[kg + 1][ci] = a.y;
        tile[kg + 2][ci] = a.z; tile[kg + 3][ci] = a.w;
        tile[kg + 4][ci] = b.x; tile[kg + 5][ci] = b.y;
        tile[kg + 6][ci] = b.z; tile[kg + 7][ci] = b.w;
    }
    __syncthreads();
    {
        const int k = threadIdx.x >> 3;             // 0..31
        const int cg = (threadIdx.x & 7) * 8;       // 0..56
        float4 o0, o1;
        o0.x = tile[k][cg + 0]; o0.y = tile[k][cg + 1];
        o0.z = tile[k][cg + 2]; o0.w = tile[k][cg + 3];
        o1.x = tile[k][cg + 4]; o1.y = tile[k][cg + 5];
        o1.z = tile[k][cg + 6]; o1.w = tile[k][cg + 7];
        *(float4*)(WTl + (size_t)(k0 + k) * KCODES + c0 + cg)     = o0;
        *(float4*)(WTl + (size_t)(k0 + k) * KCODES + c0 + cg + 4) = o1;
    }
}

#define FMA4(A, rs, wv)                                                        \
    A.x = fmaf(rs, wv.x, A.x); A.y = fmaf(rs, wv.y, A.y);                      \
    A.z = fmaf(rs, wv.z, A.z); A.w = fmaf(rs, wv.w, A.w);

__global__ __launch_bounds__(256) __attribute__((amdgpu_waves_per_eu(4)))
void rvq_level(
    const float* __restrict__ x, const float* __restrict__ W,
    const float* __restrict__ WT, const float* __restrict__ wk,
    float* __restrict__ out, float* __restrict__ avgp,
    double* __restrict__ commit, const int level) {

    __shared__ float rowR[16][132];   // residual rows, row-major (+pad; bcast-read)
    __shared__ float redf[16][17];
    __shared__ float Srow[16];
    __shared__ float wminv[16][4];    // per-wave (row) argmin partials
    __shared__ int   wmini[16][4];
    __shared__ float rowmin[16];
    __shared__ float wsum[16][4];
    __shared__ float rcpL[16];

    const int t = threadIdx.x;
    const int wave = t >> 6, lane = t & 63;
    const int c = wave * 256 + lane * 4;          // this thread's 4 codes
    const size_t base = (size_t)blockIdx.x * 16;
    const float* codesF = out + CODE_OFF;
    const float* WTl = WT + (size_t)level * DIMS * KCODES;
    const float* wkl = wk + level * KCODES;

    // ---- phase 0: stage 16 residual rows into LDS (bit-exact chain from codes) ----
    {
        const int r = t >> 4, i = t & 15;
        const size_t n = base + r;
        float4 v0 = *(const float4*)(x + n * DIMS + i * 8);
        float4 v1 = *(const float4*)(x + n * DIMS + i * 8 + 4);
        for (int j = 0; j < level; ++j) {
            const int idx = (int)codesF[n * 3 + j];
            const float* q = W + ((size_t)(j * KCODES + idx)) * DIMS + i * 8;
            const float4 q0 = *(const float4*)q;
            const float4 q1 = *(const float4*)(q + 4);
            v0.x = __fsub_rn(v0.x, q0.x); v0.y = __fsub_rn(v0.y, q0.y);
            v0.z = __fsub_rn(v0.z, q0.z); v0.w = __fsub_rn(v0.w, q0.w);
            v1.x = __fsub_rn(v1.x, q1.x); v1.y = __fsub_rn(v1.y, q1.y);
            v1.z = __fsub_rn(v1.z, q1.z); v1.w = __fsub_rn(v1.w, q1.w);
        }
        *(float4*)&rowR[r][i * 8]     = v0;
        *(float4*)&rowR[r][i * 8 + 4] = v1;
        float sq = v0.x * v0.x + v0.y * v0.y + v0.z * v0.z + v0.w * v0.w
                 + v1.x * v1.x + v1.y * v1.y + v1.z * v1.z + v1.w * v1.w;
        redf[r][i] = sq;
    }
    __syncthreads();
    if (t < 16) {
        float s = 0.f;
        for (int i = 0; i < 16; ++i) s += redf[t][i];
        Srow[t] = s;   // on-grid shift: order can't affect argmin/softmax
    }
    __syncthreads();

    // ---- phase 1: acc[r] = row_r · W_{c..c+3}, strict k-ascending fmaf chains ----
    // Software-pipelined at 4-k (half-kt) granularity with a ping-pong register
    // buffer: each consume waits only on loads issued one full 256-FMA half
    // earlier (s_waitcnt vmcnt(4), never a drain) -> L2 latency hidden even at
    // low occupancy. The fmaf sequence per accumulator component is IDENTICAL
    // to rounds 2-5 (ascending k, single chain) — only load scheduling changed.
    float4 acc[16];
#pragma unroll
    for (int r = 0; r < 16; ++r) { acc[r].x = 0.f; acc[r].y = 0.f; acc[r].z = 0.f; acc[r].w = 0.f; }

    // prologue: load half h=0 (k = 0..3) into bufA
    float4 wa0, wa1, wa2, wa3;
    {
        const float* wp = WTl + c;
        wa0 = *(const float4*)(wp + 0 * KCODES);
        wa1 = *(const float4*)(wp + 1 * KCODES);
        wa2 = *(const float4*)(wp + 2 * KCODES);
        wa3 = *(const float4*)(wp + 3 * KCODES);
    }

#pragma unroll 1
    for (int kt = 0; kt < 16; ++kt) {
        // issue loads for the odd half (k = kt*8+4 .. kt*8+7) into bufB
        const float* wpb = WTl + (size_t)(kt * 8 + 4) * KCODES + c;
        const float4 wb0 = *(const float4*)(wpb + 0 * KCODES);
        const float4 wb1 = *(const float4*)(wpb + 1 * KCODES);
        const float4 wb2 = *(const float4*)(wpb + 2 * KCODES);
        const float4 wb3 = *(const float4*)(wpb + 3 * KCODES);
        // consume even half (k = kt*8 .. kt*8+3) from bufA
#pragma unroll
        for (int r = 0; r < 16; ++r) {
            const float4 ra = *(const float4*)&rowR[r][kt * 8];      // bcast
            float4 A = acc[r];
            FMA4(A, ra.x, wa0); FMA4(A, ra.y, wa1);
            FMA4(A, ra.z, wa2); FMA4(A, ra.w, wa3);
            acc[r] = A;
        }
        // issue loads for the next even half (k = (kt+1)*8 ..) into bufA;
        // clamp on the last iteration to a safe in-bounds address (loads dead).
        const float* wpa = (kt < 15) ? (WTl + (size_t)((kt + 1) * 8) * KCODES + c)
                                     : (WTl + c);
        wa0 = *(const float4*)(wpa + 0 * KCODES);
        wa1 = *(const float4*)(wpa + 1 * KCODES);
        wa2 = *(const float4*)(wpa + 2 * KCODES);
        wa3 = *(const float4*)(wpa + 3 * KCODES);
        // consume odd half (k = kt*8+4 .. kt*8+7) from bufB
#pragma unroll
        for (int r = 0; r < 16; ++r) {
            const float4 rb = *(const float4*)&rowR[r][kt * 8 + 4];  // bcast
            float4 A = acc[r];
            FMA4(A, rb.x, wb0); FMA4(A, rb.y, wb1);
            FMA4(A, rb.z, wb2); FMA4(A, rb.w, wb3);
            acc[r] = A;
        }
    }

    // ---- phase 2: d in place, per-row argmin via lexicographic shuffle reduce ----
    const float4 wkv = *(const float4*)(wkl + c);
#pragma unroll
    for (int r = 0; r < 16; ++r) {
        const float Sr = Srow[r];
        float4 A = acc[r];
        A.x = __fadd_rn(__fsub_rn(Sr, __fmul_rn(2.0f, A.x)), wkv.x);
        A.y = __fadd_rn(__fsub_rn(Sr, __fmul_rn(2.0f, A.y)), wkv.y);
        A.z = __fadd_rn(__fsub_rn(Sr, __fmul_rn(2.0f, A.z)), wkv.z);
        A.w = __fadd_rn(__fsub_rn(Sr, __fmul_rn(2.0f, A.w)), wkv.w);
        acc[r] = A;
        float v = A.x; int bi = c;
        if (A.y < v) { v = A.y; bi = c + 1; }
        if (A.z < v) { v = A.z; bi = c + 2; }
        if (A.w < v) { v = A.w; bi = c + 3; }
#pragma unroll
        for (int m = 1; m < 64; m <<= 1) {
            const float vo = __shfl_xor(v, m, 64);
            const int   io = __shfl_xor(bi, m, 64);
            if (vo < v || (vo == v && io < bi)) { v = vo; bi = io; }
        }
        if (lane == 0) { wminv[r][wave] = v; wmini[r][wave] = bi; }
    }
    __syncthreads();
    if (t < 16) {
        float v = wminv[t][0]; int bi = wmini[t][0];
        for (int w = 1; w < 4; ++w) {
            const float vo = wminv[t][w]; const int io = wmini[t][w];
            if (vo < v || (vo == v && io < bi)) { v = vo; bi = io; }
        }
        rowmin[t] = v;
        out[CODE_OFF + (base + t) * 3 + level] = (float)bi;
    }
    __syncthreads();

    // ---- phase 3: e = exp(dmin - d) in place, row sums via shuffle ----
#pragma unroll
    for (int r = 0; r < 16; ++r) {
        const float mn = rowmin[r];
        float4 A = acc[r];
        A.x = expf(__fsub_rn(mn, A.x));
        A.y = expf(__fsub_rn(mn, A.y));
        A.z = expf(__fsub_rn(mn, A.z));
        A.w = expf(__fsub_rn(mn, A.w));
        acc[r] = A;
        float s = (A.x + A.y) + (A.z + A.w);
#pragma unroll
        for (int m = 1; m < 64; m <<= 1) s += __shfl_xor(s, m, 64);
        if (lane == 0) wsum[r][wave] = s;
    }
    __syncthreads();
    if (t < 16) {
        const float L = (wsum[t][0] + wsum[t][1]) + (wsum[t][2] + wsum[t][3]);
        rcpL[t] = 1.0f / L;
    }
    if (t == 64) {   // commit partial: d at argmin == ||r - q||^2 (loss tolerance loose)
        double cs = 0.0;
        for (int r = 0; r < 16; ++r) cs += (double)rowmin[r];
        atomicAdd(&commit[level], cs);
    }
    __syncthreads();

    // ---- phase 4: avg_probs partials (fp32 atomics, one per code per block) ----
    {
        float s0 = 0.f, s1 = 0.f, s2 = 0.f, s3 = 0.f;
#pragma unroll
        for (int r = 0; r < 16; ++r) {
            const float rl = rcpL[r];
            s0 = fmaf(acc[r].x, rl, s0);
            s1 = fmaf(acc[r].y, rl, s1);
            s2 = fmaf(acc[r].z, rl, s2);
            s3 = fmaf(acc[r].w, rl, s3);
        }
        atomicAdd(&avgp[level * KCODES + c + 0], s0);
        atomicAdd(&avgp[level * KCODES + c + 1], s1);
        atomicAdd(&avgp[level * KCODES + c + 2], s2);
        atomicAdd(&avgp[level * KCODES + c + 3], s3);
    }
}

__global__ __launch_bounds__(256) void finalize_kernel(const float* __restrict__ avgp,
                                                       const double* __restrict__ commit,
                                                       float* __restrict__ out) {
    __shared__ double red[256];
    __shared__ float  kls[3];
    const int t = threadIdx.x;
    for (int l = 0; l < 3; ++l) {
        double p = 0.0;
        for (int k = t; k < KCODES; k += 256) {
            const float avg = avgp[l * KCODES + k] * (1.0f / 131072.0f);
            p += (double)avg * log((double)avg * 1024.0 + 1e-8);
        }
        red[t] = p; __syncthreads();
        for (int off = 128; off >= 1; off >>= 1) {
            if (t < off) red[t] += red[t + off];
            __syncthreads();
        }
        if (t == 0) kls[l] = (float)red[0];
        __syncthreads();
    }
    if (t == 0) {
        float cv = 0.f, u = 0.f;
        for (int l = 0; l < 3; ++l) {
            const float m = (float)(commit[l] * (1.0 / 16777216.0));
            cv = __fadd_rn(cv, m);                      // + mean((sg(r)-q)^2)
            cv = __fadd_rn(cv, __fmul_rn(0.25f, m));    // + BETA * mean((r-sg(q))^2)
            u = __fadd_rn(u, __fmul_rn(1e-3f, kls[l]));
        }
        out[SCAL_OFF]     = cv;
        out[SCAL_OFF + 1] = u;
    }
}

__global__ __launch_bounds__(256) void gather_kernel(const float* __restrict__ W,
                                                     float* __restrict__ out) {
    const size_t g = (size_t)blockIdx.x * 256 + threadIdx.x;   // f4 index
    const size_t n = g >> 5;
    const int f = (int)(g & 31);
    const float* codes = out + CODE_OFF + n * 3;
    const int c0 = (int)codes[0], c1 = (int)codes[1], c2 = (int)codes[2];
    const float4 a = *(const float4*)(W + (size_t)c0 * DIMS + 4 * f);
    const float4 b = *(const float4*)(W + (size_t)(KCODES + c1) * DIMS + 4 * f);
    const float4 c = *(const float4*)(W + (size_t)(2 * KCODES + c2) * DIMS + 4 * f);
    float4 o;   // ((q1 + q2) + q3), fp32 like reference
    o.x = __fadd_rn(__fadd_rn(a.x, b.x), c.x);
    o.y = __fadd_rn(__fadd_rn(a.y, b.y), c.y);
    o.z = __fadd_rn(__fadd_rn(a.z, b.z), c.z);
    o.w = __fadd_rn(__fadd_rn(a.w, b.w), c.w);
    *(float4*)(out + n * DIMS + 4 * f) = o;
}

extern "C" void kernel_launch(void* const* d_in, const int* in_sizes, int n_in,
                              void* d_out, int out_size, void* d_ws, size_t ws_size,
                              hipStream_t stream) {
    const float* x = (const float*)d_in[0];
    const float* W = (const float*)d_in[1];
    float* out = (float*)d_out;
    float*  avgp   = (float*)d_ws;
    double* commit = (double*)((char*)d_ws + WS_COMMIT_OFF);
    float*  wkp    = (float*)((char*)d_ws + WS_WK_OFF);
    float*  WT     = (float*)((char*)d_ws + WS_WT_OFF);

    hipLaunchKernelGGL(init_acc, dim3(1), dim3(256), 0, stream, avgp, commit);
    hipLaunchKernelGGL(wnorm_kernel, dim3(768), dim3(256), 0, stream, W, wkp);
    hipLaunchKernelGGL(transpose_w, dim3(16, 4, 3), dim3(256), 0, stream, W, WT);
    for (int l = 0; l < NLEV; ++l)
        hipLaunchKernelGGL(rvq_level, dim3(NROWS / 16), dim3(256), 0, stream,
                           x, W, WT, wkp, out, avgp, commit, l);
    hipLaunchKernelGGL(finalize_kernel, dim3(1), dim3(256), 0, stream, avgp, commit, out);
    hipLaunchKernelGGL(gather_kernel, dim3((NROWS * 32) / 256), dim3(256), 0, stream, W, out);
}

// Round 3
// 2874.804 us; speedup vs baseline: 2.5140x; 2.5140x over previous
//
#include <hip/hip_runtime.h>

// ResidualVectorQuantizer: N=131072, DIM=128, LEVELS=3, K=1024, BETA=0.25, USAGE_REG=1e-3
// Outputs (flat fp32 in d_out): quantized [N*128] | codes [N*3] | commit | usage
//
// Numerics contract with the np fp32 reference (validated in rounds 2-4 — do not change):
//  - m = x·W_k: strict sequential fmaf chain over k=0..127, single accumulator.
//  - d = (S - 2*m) + w via __fsub_rn/__fmul_rn/__fadd_rn (no contraction).
//  - argmin: first occurrence on ties (lexicographic (value, index) min).
//  - residual chain (x - q0) - q1 elementwise fp32, recomputed from codes per level.
//  - losses: tolerance loose (~2%); commit = sum of d at argmin; avgp fp32; KL f64.
//
// Round 8 post-mortem of rounds 6-7: BOTH waves-per-eu spellings (launch_bounds
// (256,4) and amdgpu_waves_per_eu(4)) set only a MINIMUM; the allocator targeted
// the range max (8 waves -> 64-reg budget) and scratch-spilled the ~116-reg
// ping-pong live set (WRITE 7 GB, spill-BW-bound at 2.8 TB/s = the whole 2.7 ms).
// Structural fix instead of allocator hints: split the 16-row accumulator tile
// into TWO sequential 8-row groups. Per group: acc 32 + bufA 16 + bufB 16 +
// addressing ~ 88 regs -> fits the 96-reg granule the default allocator already
// handled at round 0 (VGPR=92, zero spill). Keeps the ping-pong pipeline (the
// real latency fix). WT columns re-read once per group (L2 traffic x2, ~240 us
// overlapped under the 440 us FMA floor). Per-row math order unchanged ->
// numerics identical. Spill check: WRITE_SIZE must be ~133 MB (atomics only).

#define NROWS   131072
#define DIMS    128
#define KCODES  1024
#define NLEV    3

#define QF_OFF   ((size_t)NROWS * DIMS)          // 16777216
#define CODE_OFF QF_OFF
#define SCAL_OFF (QF_OFF + (size_t)NROWS * 3)    // 17170432

// ---------------- ws layout ----------------
// avgp   : 3*1024 floats  @ 0        (12288 B)
// commit : 3 doubles      @ 12288    (24 B)
// wk     : 3*1024 floats  @ 12320    (12288 B)
// WT     : 3*128*1024 fl  @ 24608    (1572864 B)  k-major codebooks
#define WS_COMMIT_OFF 12288
#define WS_WK_OFF     12320
#define WS_WT_OFF     24608

__global__ __launch_bounds__(256) void init_acc(float* avgp, double* commit) {
    for (int i = threadIdx.x; i < 3072; i += 256) avgp[i] = 0.0f;
    if (threadIdx.x < 3) commit[threadIdx.x] = 0.0;
}

__global__ __launch_bounds__(256) void wnorm_kernel(const float* __restrict__ W,
                                                    float* __restrict__ wk) {
    const int wave = threadIdx.x >> 6, lane = threadIdx.x & 63;
    const int c = blockIdx.x * 4 + wave;          // 0..3071 (level*1024 + k)
    const float2 v = *(const float2*)(W + (size_t)c * DIMS + 2 * lane);
    float s = v.x * v.x + v.y * v.y;
#pragma unroll
    for (int m = 32; m >= 1; m >>= 1) s += __shfl_xor(s, m, 64);
    if (lane == 0) wk[c] = s;
}

// WT[l][k][c] = W[l][c][k]
__global__ __launch_bounds__(256) void transpose_w(const float* __restrict__ W,
                                                   float* __restrict__ WT) {
    __shared__ float tile[32][65];
    const int l = blockIdx.z, k0 = blockIdx.y * 32, c0 = blockIdx.x * 64;
    const float* Wl = W + (size_t)l * KCODES * DIMS;
    float* WTl = WT + (size_t)l * DIMS * KCODES;
    {
        const int ci = threadIdx.x >> 2;            // 0..63
        const int kg = (threadIdx.x & 3) * 8;       // 0,8,16,24
        const float4 a = *(const float4*)(Wl + (size_t)(c0 + ci) * DIMS + k0 + kg);
        const float4 b = *(const float4*)(Wl + (size_t)(c0 + ci) * DIMS + k0 + kg + 4);
        tile[kg + 0][ci] = a.x; tile[kg + 1][ci] = a.y;
        tile[kg + 2][ci] = a.z; tile[kg + 3][ci] = a.w;
        tile[kg + 4][ci] = b.x; tile[kg + 5][ci] = b.y;
        tile[kg + 6][ci] = b.z; tile[kg + 7][ci] = b.w;
    }
    __syncthreads();
    {
        const int k = threadIdx.x >> 3;             // 0..31
        const int cg = (threadIdx.x & 7) * 8;       // 0..56
        float4 o0, o1;
        o0.x = tile[k][cg + 0]; o0.y = tile[k][cg + 1];
        o0.z = tile[k][cg + 2]; o0.w = tile[k][cg + 3];
        o1.x = tile[k][cg + 4]; o1.y = tile[k][cg + 5];
        o1.z = tile[k][cg + 6]; o1.w = tile[k][cg + 7];
        *(float4*)(WTl + (size_t)(k0 + k) * KCODES + c0 + cg)     = o0;
        *(float4*)(WTl + (size_t)(k0 + k) * KCODES + c0 + cg + 4) = o1;
    }
}

#define FMA4(A, rs, wv)                                                        \
    A.x = fmaf(rs, wv.x, A.x); A.y = fmaf(rs, wv.y, A.y);                      \
    A.z = fmaf(rs, wv.z, A.z); A.w = fmaf(rs, wv.w, A.w);

__global__ __launch_bounds__(256) void rvq_level(
    const float* __restrict__ x, const float* __restrict__ W,
    const float* __restrict__ WT, const float* __restrict__ wk,
    float* __restrict__ out, float* __restrict__ avgp,
    double* __restrict__ commit, const int level) {

    __shared__ float rowR[16][132];   // residual rows, row-major (+pad; bcast-read)
    __shared__ float redf[16][17];
    __shared__ float Srow[16];
    __shared__ float wminv[16][4];    // per-wave (row) argmin partials
    __shared__ int   wmini[16][4];
    __shared__ float rowmin[16];
    __shared__ float wsum[16][4];
    __shared__ float rcpL[16];

    const int t = threadIdx.x;
    const int wave = t >> 6, lane = t & 63;
    const int c = wave * 256 + lane * 4;          // this thread's 4 codes
    const size_t base = (size_t)blockIdx.x * 16;
    const float* codesF = out + CODE_OFF;
    const float* WTl = WT + (size_t)level * DIMS * KCODES;
    const float* wkl = wk + level * KCODES;

    // ---- phase 0: stage 16 residual rows into LDS (bit-exact chain from codes) ----
    {
        const int r = t >> 4, i = t & 15;
        const size_t n = base + r;
        float4 v0 = *(const float4*)(x + n * DIMS + i * 8);
        float4 v1 = *(const float4*)(x + n * DIMS + i * 8 + 4);
        for (int j = 0; j < level; ++j) {
            const int idx = (int)codesF[n * 3 + j];
            const float* q = W + ((size_t)(j * KCODES + idx)) * DIMS + i * 8;
            const float4 q0 = *(const float4*)q;
            const float4 q1 = *(const float4*)(q + 4);
            v0.x = __fsub_rn(v0.x, q0.x); v0.y = __fsub_rn(v0.y, q0.y);
            v0.z = __fsub_rn(v0.z, q0.z); v0.w = __fsub_rn(v0.w, q0.w);
            v1.x = __fsub_rn(v1.x, q1.x); v1.y = __fsub_rn(v1.y, q1.y);
            v1.z = __fsub_rn(v1.z, q1.z); v1.w = __fsub_rn(v1.w, q1.w);
        }
        *(float4*)&rowR[r][i * 8]     = v0;
        *(float4*)&rowR[r][i * 8 + 4] = v1;
        float sq = v0.x * v0.x + v0.y * v0.y + v0.z * v0.z + v0.w * v0.w
                 + v1.x * v1.x + v1.y * v1.y + v1.z * v1.z + v1.w * v1.w;
        redf[r][i] = sq;
    }
    __syncthreads();
    if (t < 16) {
        float s = 0.f;
        for (int i = 0; i < 16; ++i) s += redf[t][i];
        Srow[t] = s;   // on-grid shift: order can't affect argmin/softmax
    }
    __syncthreads();

    const float4 wkv = *(const float4*)(wkl + c);
    float s0 = 0.f, s1 = 0.f, s2 = 0.f, s3 = 0.f;   // phase-4 partials across groups

    // ---- row-group loop: 2 groups of 8 rows. Per group live set ~88 regs
    // (acc 32 + bufA 16 + bufB 16 + bcast/addr) -> no spill at default bounds. ----
#pragma unroll 1
    for (int rg = 0; rg < 2; ++rg) {
        const int r0 = rg * 8;

        // ---- phase 1: acc[r] = row_{r0+r} · W_{c..c+3}, strict k-ascending chains,
        // ping-pong double-buffered WT loads (consume waits only on loads issued
        // one 128-FMA half earlier; never a full vmcnt drain). ----
        float4 acc[8];
#pragma unroll
        for (int r = 0; r < 8; ++r) { acc[r].x = 0.f; acc[r].y = 0.f; acc[r].z = 0.f; acc[r].w = 0.f; }

        // prologue: load half h=0 (k = 0..3) into bufA
        float4 wa0, wa1, wa2, wa3;
        {
            const float* wp = WTl + c;
            wa0 = *(const float4*)(wp + 0 * KCODES);
            wa1 = *(const float4*)(wp + 1 * KCODES);
            wa2 = *(const float4*)(wp + 2 * KCODES);
            wa3 = *(const float4*)(wp + 3 * KCODES);
        }

#pragma unroll 1
        for (int kt = 0; kt < 16; ++kt) {
            // issue loads for the odd half (k = kt*8+4 .. kt*8+7) into bufB
            const float* wpb = WTl + (size_t)(kt * 8 + 4) * KCODES + c;
            const float4 wb0 = *(const float4*)(wpb + 0 * KCODES);
            const float4 wb1 = *(const float4*)(wpb + 1 * KCODES);
            const float4 wb2 = *(const float4*)(wpb + 2 * KCODES);
            const float4 wb3 = *(const float4*)(wpb + 3 * KCODES);
            // consume even half from bufA
#pragma unroll
            for (int r = 0; r < 8; ++r) {
                const float4 ra = *(const float4*)&rowR[r0 + r][kt * 8];      // bcast
                float4 A = acc[r];
                FMA4(A, ra.x, wa0); FMA4(A, ra.y, wa1);
                FMA4(A, ra.z, wa2); FMA4(A, ra.w, wa3);
                acc[r] = A;
            }
            // issue loads for the next even half into bufA (clamped, dead on last iter)
            const float* wpa = (kt < 15) ? (WTl + (size_t)((kt + 1) * 8) * KCODES + c)
                                         : (WTl + c);
            wa0 = *(const float4*)(wpa + 0 * KCODES);
            wa1 = *(const float4*)(wpa + 1 * KCODES);
            wa2 = *(const float4*)(wpa + 2 * KCODES);
            wa3 = *(const float4*)(wpa + 3 * KCODES);
            // consume odd half from bufB
#pragma unroll
            for (int r = 0; r < 8; ++r) {
                const float4 rb = *(const float4*)&rowR[r0 + r][kt * 8 + 4];  // bcast
                float4 A = acc[r];
                FMA4(A, rb.x, wb0); FMA4(A, rb.y, wb1);
                FMA4(A, rb.z, wb2); FMA4(A, rb.w, wb3);
                acc[r] = A;
            }
        }

        // ---- phase 2: d in place, per-row argmin (lexicographic shuffle reduce) ----
#pragma unroll
        for (int r = 0; r < 8; ++r) {
            const float Sr = Srow[r0 + r];
            float4 A = acc[r];
            A.x = __fadd_rn(__fsub_rn(Sr, __fmul_rn(2.0f, A.x)), wkv.x);
            A.y = __fadd_rn(__fsub_rn(Sr, __fmul_rn(2.0f, A.y)), wkv.y);
            A.z = __fadd_rn(__fsub_rn(Sr, __fmul_rn(2.0f, A.z)), wkv.z);
            A.w = __fadd_rn(__fsub_rn(Sr, __fmul_rn(2.0f, A.w)), wkv.w);
            acc[r] = A;
            float v = A.x; int bi = c;
            if (A.y < v) { v = A.y; bi = c + 1; }
            if (A.z < v) { v = A.z; bi = c + 2; }
            if (A.w < v) { v = A.w; bi = c + 3; }
#pragma unroll
            for (int m = 1; m < 64; m <<= 1) {
                const float vo = __shfl_xor(v, m, 64);
                const int   io = __shfl_xor(bi, m, 64);
                if (vo < v || (vo == v && io < bi)) { v = vo; bi = io; }
            }
            if (lane == 0) { wminv[r0 + r][wave] = v; wmini[r0 + r][wave] = bi; }
        }
        __syncthreads();
        if (t < 8) {
            float v = wminv[r0 + t][0]; int bi = wmini[r0 + t][0];
            for (int w = 1; w < 4; ++w) {
                const float vo = wminv[r0 + t][w]; const int io = wmini[r0 + t][w];
                if (vo < v || (vo == v && io < bi)) { v = vo; bi = io; }
            }
            rowmin[r0 + t] = v;
            out[CODE_OFF + (base + r0 + t) * 3 + level] = (float)bi;
        }
        __syncthreads();

        // ---- phase 3: e = exp(dmin - d) in place, row sums via shuffle ----
#pragma unroll
        for (int r = 0; r < 8; ++r) {
            const float mn = rowmin[r0 + r];
            float4 A = acc[r];
            A.x = expf(__fsub_rn(mn, A.x));
            A.y = expf(__fsub_rn(mn, A.y));
            A.z = expf(__fsub_rn(mn, A.z));
            A.w = expf(__fsub_rn(mn, A.w));
            acc[r] = A;
            float s = (A.x + A.y) + (A.z + A.w);
#pragma unroll
            for (int m = 1; m < 64; m <<= 1) s += __shfl_xor(s, m, 64);
            if (lane == 0) wsum[r0 + r][wave] = s;
        }
        __syncthreads();
        if (t < 8) {
            const float L = (wsum[r0 + t][0] + wsum[r0 + t][1])
                          + (wsum[r0 + t][2] + wsum[r0 + t][3]);
            rcpL[r0 + t] = 1.0f / L;
        }
        __syncthreads();

        // ---- phase 4 partial: accumulate avg_probs contributions in registers ----
#pragma unroll
        for (int r = 0; r < 8; ++r) {
            const float rl = rcpL[r0 + r];
            s0 = fmaf(acc[r].x, rl, s0);
            s1 = fmaf(acc[r].y, rl, s1);
            s2 = fmaf(acc[r].z, rl, s2);
            s3 = fmaf(acc[r].w, rl, s3);
        }
    }

    // ---- commit partial: d at argmin == ||r - q||^2 (loss tolerance loose) ----
    if (t == 64) {
        double cs = 0.0;
        for (int r = 0; r < 16; ++r) cs += (double)rowmin[r];
        atomicAdd(&commit[level], cs);
    }

    // ---- avg_probs atomics: one per code per block ----
    atomicAdd(&avgp[level * KCODES + c + 0], s0);
    atomicAdd(&avgp[level * KCODES + c + 1], s1);
    atomicAdd(&avgp[level * KCODES + c + 2], s2);
    atomicAdd(&avgp[level * KCODES + c + 3], s3);
}

__global__ __launch_bounds__(256) void finalize_kernel(const float* __restrict__ avgp,
                                                       const double* __restrict__ commit,
                                                       float* __restrict__ out) {
    __shared__ double red[256];
    __shared__ float  kls[3];
    const int t = threadIdx.x;
    for (int l = 0; l < 3; ++l) {
        double p = 0.0;
        for (int k = t; k < KCODES; k += 256) {
            const float avg = avgp[l * KCODES + k] * (1.0f / 131072.0f);
            p += (double)avg * log((double)avg * 1024.0 + 1e-8);
        }
        red[t] = p; __syncthreads();
        for (int off = 128; off >= 1; off >>= 1) {
            if (t < off) red[t] += red[t + off];
            __syncthreads();
        }
        if (t == 0) kls[l] = (float)red[0];
        __syncthreads();
    }
    if (t == 0) {
        float cv = 0.f, u = 0.f;
        for (int l = 0; l < 3; ++l) {
            const float m = (float)(commit[l] * (1.0 / 16777216.0));
            cv = __fadd_rn(cv, m);                      // + mean((sg(r)-q)^2)
            cv = __fadd_rn(cv, __fmul_rn(0.25f, m));    // + BETA * mean((r-sg(q))^2)
            u = __fadd_rn(u, __fmul_rn(1e-3f, kls[l]));
        }
        out[SCAL_OFF]     = cv;
        out[SCAL_OFF + 1] = u;
    }
}

__global__ __launch_bounds__(256) void gather_kernel(const float* __restrict__ W,
                                                     float* __restrict__ out) {
    const size_t g = (size_t)blockIdx.x * 256 + threadIdx.x;   // f4 index
    const size_t n = g >> 5;
    const int f = (int)(g & 31);
    const float* codes = out + CODE_OFF + n * 3;
    const int c0 = (int)codes[0], c1 = (int)codes[1], c2 = (int)codes[2];
    const float4 a = *(const float4*)(W + (size_t)c0 * DIMS + 4 * f);
    const float4 b = *(const float4*)(W + (size_t)(KCODES + c1) * DIMS + 4 * f);
    const float4 c = *(const float4*)(W + (size_t)(2 * KCODES + c2) * DIMS + 4 * f);
    float4 o;   // ((q1 + q2) + q3), fp32 like reference
    o.x = __fadd_rn(__fadd_rn(a.x, b.x), c.x);
    o.y = __fadd_rn(__fadd_rn(a.y, b.y), c.y);
    o.z = __fadd_rn(__fadd_rn(a.z, b.z), c.z);
    o.w = __fadd_rn(__fadd_rn(a.w, b.w), c.w);
    *(float4*)(out + n * DIMS + 4 * f) = o;
}

extern "C" void kernel_launch(void* const* d_in, const int* in_sizes, int n_in,
                              void* d_out, int out_size, void* d_ws, size_t ws_size,
                              hipStream_t stream) {
    const float* x = (const float*)d_in[0];
    const float* W = (const float*)d_in[1];
    float* out = (float*)d_out;
    float*  avgp   = (float*)d_ws;
    double* commit = (double*)((char*)d_ws + WS_COMMIT_OFF);
    float*  wkp    = (float*)((char*)d_ws + WS_WK_OFF);
    float*  WT     = (float*)((char*)d_ws + WS_WT_OFF);

    hipLaunchKernelGGL(init_acc, dim3(1), dim3(256), 0, stream, avgp, commit);
    hipLaunchKernelGGL(wnorm_kernel, dim3(768), dim3(256), 0, stream, W, wkp);
    hipLaunchKernelGGL(transpose_w, dim3(16, 4, 3), dim3(256), 0, stream, W, WT);
    for (int l = 0; l < NLEV; ++l)
        hipLaunchKernelGGL(rvq_level, dim3(NROWS / 16), dim3(256), 0, stream,
                           x, W, WT, wkp, out, avgp, commit, l);
    hipLaunchKernelGGL(finalize_kernel, dim3(1), dim3(256), 0, stream, avgp, commit, out);
    hipLaunchKernelGGL(gather_kernel, dim3((NROWS * 32) / 256), dim3(256), 0, stream, W, out);
}

// Round 4
// 2855.882 us; speedup vs baseline: 2.5307x; 1.0066x over previous
//
#include <hip/hip_runtime.h>

// ResidualVectorQuantizer: N=131072, DIM=128, LEVELS=3, K=1024, BETA=0.25, USAGE_REG=1e-3
// Outputs (flat fp32 in d_out): quantized [N*128] | codes [N*3] | commit | usage
//
// Numerics contract with the np fp32 reference (validated in rounds 2-4 — do not change):
//  - m = x·W_k: strict sequential fmaf chain over k=0..127, single accumulator.
//  - d = (S - 2*m) + w via __fsub_rn/__fmul_rn/__fadd_rn (no contraction).
//  - argmin: first occurrence on ties (lexicographic (value, index) min).
//  - residual chain (x - q0) - q1 elementwise fp32, recomputed from codes per level.
//  - losses: tolerance loose (~2%); commit = sum of d at argmin; avgp fp32; KL f64.
//
// Round 9 post-mortem of round 8 (8-row groups, default bounds): spill gone
// (WRITE back to 133 MB) but VGPR_Count=60 == the NON-pipelined live set, and
// VALU-cycle arithmetic shows ~500K cycles/SIMD of non-FMA VALU (~= the FMA work
// itself): the allocator compacted to 8 waves/SIMD by defeating the ping-pong
// (sinking prefetch loads / AGPR-parking the second buffer with accvgpr churn).
// Three rounds of evidence say the allocator ALWAYS chases max occupancy:
//  - min-only bounds (4): scratch-spills to 64 regs (rounds 6-7, 7 GB writes)
//  - no bounds: compacts to 60 regs, pipeline defeated (round 8)
// Fix: amdgpu_waves_per_eu(4, 4) — the explicit MAX removes the 8-wave target.
// Budget 512/4 = 128 regs; pipelined live set ~84-100 fits with slack -> no
// spill, no AGPR games, loads stay hoisted. Also: FMA4 now updates acc[r] in
// place (same chain order, removes any float4 copy-mov risk).
// Checks: VGPR must read 96-128; WRITE must stay ~133 MB.

#define NROWS   131072
#define DIMS    128
#define KCODES  1024
#define NLEV    3

#define QF_OFF   ((size_t)NROWS * DIMS)          // 16777216
#define CODE_OFF QF_OFF
#define SCAL_OFF (QF_OFF + (size_t)NROWS * 3)    // 17170432

// ---------------- ws layout ----------------
// avgp   : 3*1024 floats  @ 0        (12288 B)
// commit : 3 doubles      @ 12288    (24 B)
// wk     : 3*1024 floats  @ 12320    (12288 B)
// WT     : 3*128*1024 fl  @ 24608    (1572864 B)  k-major codebooks
#define WS_COMMIT_OFF 12288
#define WS_WK_OFF     12320
#define WS_WT_OFF     24608

__global__ __launch_bounds__(256) void init_acc(float* avgp, double* commit) {
    for (int i = threadIdx.x; i < 3072; i += 256) avgp[i] = 0.0f;
    if (threadIdx.x < 3) commit[threadIdx.x] = 0.0;
}

__global__ __launch_bounds__(256) void wnorm_kernel(const float* __restrict__ W,
                                                    float* __restrict__ wk) {
    const int wave = threadIdx.x >> 6, lane = threadIdx.x & 63;
    const int c = blockIdx.x * 4 + wave;          // 0..3071 (level*1024 + k)
    const float2 v = *(const float2*)(W + (size_t)c * DIMS + 2 * lane);
    float s = v.x * v.x + v.y * v.y;
#pragma unroll
    for (int m = 32; m >= 1; m >>= 1) s += __shfl_xor(s, m, 64);
    if (lane == 0) wk[c] = s;
}

// WT[l][k][c] = W[l][c][k]
__global__ __launch_bounds__(256) void transpose_w(const float* __restrict__ W,
                                                   float* __restrict__ WT) {
    __shared__ float tile[32][65];
    const int l = blockIdx.z, k0 = blockIdx.y * 32, c0 = blockIdx.x * 64;
    const float* Wl = W + (size_t)l * KCODES * DIMS;
    float* WTl = WT + (size_t)l * DIMS * KCODES;
    {
        const int ci = threadIdx.x >> 2;            // 0..63
        const int kg = (threadIdx.x & 3) * 8;       // 0,8,16,24
        const float4 a = *(const float4*)(Wl + (size_t)(c0 + ci) * DIMS + k0 + kg);
        const float4 b = *(const float4*)(Wl + (size_t)(c0 + ci) * DIMS + k0 + kg + 4);
        tile[kg + 0][ci] = a.x; tile[kg + 1][ci] = a.y;
        tile[kg + 2][ci] = a.z; tile[kg + 3][ci] = a.w;
        tile[kg + 4][ci] = b.x; tile[kg + 5][ci] = b.y;
        tile[kg + 6][ci] = b.z; tile[kg + 7][ci] = b.w;
    }
    __syncthreads();
    {
        const int k = threadIdx.x >> 3;             // 0..31
        const int cg = (threadIdx.x & 7) * 8;       // 0..56
        float4 o0, o1;
        o0.x = tile[k][cg + 0]; o0.y = tile[k][cg + 1];
        o0.z = tile[k][cg + 2]; o0.w = tile[k][cg + 3];
        o1.x = tile[k][cg + 4]; o1.y = tile[k][cg + 5];
        o1.z = tile[k][cg + 6]; o1.w = tile[k][cg + 7];
        *(float4*)(WTl + (size_t)(k0 + k) * KCODES + c0 + cg)     = o0;
        *(float4*)(WTl + (size_t)(k0 + k) * KCODES + c0 + cg + 4) = o1;
    }
}

// In-place FMA on the accumulator (same fmaf chain order as all prior rounds).
#define FMA4(A, rs, wv)                                                        \
    A.x = fmaf(rs, wv.x, A.x); A.y = fmaf(rs, wv.y, A.y);                      \
    A.z = fmaf(rs, wv.z, A.z); A.w = fmaf(rs, wv.w, A.w);

__global__ __launch_bounds__(256) __attribute__((amdgpu_waves_per_eu(4, 4)))
void rvq_level(
    const float* __restrict__ x, const float* __restrict__ W,
    const float* __restrict__ WT, const float* __restrict__ wk,
    float* __restrict__ out, float* __restrict__ avgp,
    double* __restrict__ commit, const int level) {

    __shared__ float rowR[16][132];   // residual rows, row-major (+pad; bcast-read)
    __shared__ float redf[16][17];
    __shared__ float Srow[16];
    __shared__ float wminv[16][4];    // per-wave (row) argmin partials
    __shared__ int   wmini[16][4];
    __shared__ float rowmin[16];
    __shared__ float wsum[16][4];
    __shared__ float rcpL[16];

    const int t = threadIdx.x;
    const int wave = t >> 6, lane = t & 63;
    const int c = wave * 256 + lane * 4;          // this thread's 4 codes
    const size_t base = (size_t)blockIdx.x * 16;
    const float* codesF = out + CODE_OFF;
    const float* WTl = WT + (size_t)level * DIMS * KCODES;
    const float* wkl = wk + level * KCODES;

    // ---- phase 0: stage 16 residual rows into LDS (bit-exact chain from codes) ----
    {
        const int r = t >> 4, i = t & 15;
        const size_t n = base + r;
        float4 v0 = *(const float4*)(x + n * DIMS + i * 8);
        float4 v1 = *(const float4*)(x + n * DIMS + i * 8 + 4);
        for (int j = 0; j < level; ++j) {
            const int idx = (int)codesF[n * 3 + j];
            const float* q = W + ((size_t)(j * KCODES + idx)) * DIMS + i * 8;
            const float4 q0 = *(const float4*)q;
            const float4 q1 = *(const float4*)(q + 4);
            v0.x = __fsub_rn(v0.x, q0.x); v0.y = __fsub_rn(v0.y, q0.y);
            v0.z = __fsub_rn(v0.z, q0.z); v0.w = __fsub_rn(v0.w, q0.w);
            v1.x = __fsub_rn(v1.x, q1.x); v1.y = __fsub_rn(v1.y, q1.y);
            v1.z = __fsub_rn(v1.z, q1.z); v1.w = __fsub_rn(v1.w, q1.w);
        }
        *(float4*)&rowR[r][i * 8]     = v0;
        *(float4*)&rowR[r][i * 8 + 4] = v1;
        float sq = v0.x * v0.x + v0.y * v0.y + v0.z * v0.z + v0.w * v0.w
                 + v1.x * v1.x + v1.y * v1.y + v1.z * v1.z + v1.w * v1.w;
        redf[r][i] = sq;
    }
    __syncthreads();
    if (t < 16) {
        float s = 0.f;
        for (int i = 0; i < 16; ++i) s += redf[t][i];
        Srow[t] = s;   // on-grid shift: order can't affect argmin/softmax
    }
    __syncthreads();

    const float4 wkv = *(const float4*)(wkl + c);
    float s0 = 0.f, s1 = 0.f, s2 = 0.f, s3 = 0.f;   // phase-4 partials across groups

    // ---- row-group loop: 2 groups of 8 rows. Pipelined live set ~84-100 regs;
    // waves_per_eu(4,4) -> 128-reg budget -> fits with slack, no spill/AGPR. ----
#pragma unroll 1
    for (int rg = 0; rg < 2; ++rg) {
        const int r0 = rg * 8;

        // ---- phase 1: acc[r] = row_{r0+r} · W_{c..c+3}, strict k-ascending chains,
        // ping-pong double-buffered WT loads (consume waits only on loads issued
        // one 128-FMA half earlier; never a full vmcnt drain). ----
        float4 acc[8];
#pragma unroll
        for (int r = 0; r < 8; ++r) { acc[r].x = 0.f; acc[r].y = 0.f; acc[r].z = 0.f; acc[r].w = 0.f; }

        // prologue: load half h=0 (k = 0..3) into bufA
        float4 wa0, wa1, wa2, wa3;
        {
            const float* wp = WTl + c;
            wa0 = *(const float4*)(wp + 0 * KCODES);
            wa1 = *(const float4*)(wp + 1 * KCODES);
            wa2 = *(const float4*)(wp + 2 * KCODES);
            wa3 = *(const float4*)(wp + 3 * KCODES);
        }

#pragma unroll 1
        for (int kt = 0; kt < 16; ++kt) {
            // issue loads for the odd half (k = kt*8+4 .. kt*8+7) into bufB
            const float* wpb = WTl + (size_t)(kt * 8 + 4) * KCODES + c;
            const float4 wb0 = *(const float4*)(wpb + 0 * KCODES);
            const float4 wb1 = *(const float4*)(wpb + 1 * KCODES);
            const float4 wb2 = *(const float4*)(wpb + 2 * KCODES);
            const float4 wb3 = *(const float4*)(wpb + 3 * KCODES);
            // consume even half from bufA
#pragma unroll
            for (int r = 0; r < 8; ++r) {
                const float4 ra = *(const float4*)&rowR[r0 + r][kt * 8];      // bcast
                FMA4(acc[r], ra.x, wa0); FMA4(acc[r], ra.y, wa1);
                FMA4(acc[r], ra.z, wa2); FMA4(acc[r], ra.w, wa3);
            }
            // issue loads for the next even half into bufA (clamped, dead on last iter)
            const float* wpa = (kt < 15) ? (WTl + (size_t)((kt + 1) * 8) * KCODES + c)
                                         : (WTl + c);
            wa0 = *(const float4*)(wpa + 0 * KCODES);
            wa1 = *(const float4*)(wpa + 1 * KCODES);
            wa2 = *(const float4*)(wpa + 2 * KCODES);
            wa3 = *(const float4*)(wpa + 3 * KCODES);
            // consume odd half from bufB
#pragma unroll
            for (int r = 0; r < 8; ++r) {
                const float4 rb = *(const float4*)&rowR[r0 + r][kt * 8 + 4];  // bcast
                FMA4(acc[r], rb.x, wb0); FMA4(acc[r], rb.y, wb1);
                FMA4(acc[r], rb.z, wb2); FMA4(acc[r], rb.w, wb3);
            }
        }

        // ---- phase 2: d in place, per-row argmin (lexicographic shuffle reduce) ----
#pragma unroll
        for (int r = 0; r < 8; ++r) {
            const float Sr = Srow[r0 + r];
            float4 A = acc[r];
            A.x = __fadd_rn(__fsub_rn(Sr, __fmul_rn(2.0f, A.x)), wkv.x);
            A.y = __fadd_rn(__fsub_rn(Sr, __fmul_rn(2.0f, A.y)), wkv.y);
            A.z = __fadd_rn(__fsub_rn(Sr, __fmul_rn(2.0f, A.z)), wkv.z);
            A.w = __fadd_rn(__fsub_rn(Sr, __fmul_rn(2.0f, A.w)), wkv.w);
            acc[r] = A;
            float v = A.x; int bi = c;
            if (A.y < v) { v = A.y; bi = c + 1; }
            if (A.z < v) { v = A.z; bi = c + 2; }
            if (A.w < v) { v = A.w; bi = c + 3; }
#pragma unroll
            for (int m = 1; m < 64; m <<= 1) {
                const float vo = __shfl_xor(v, m, 64);
                const int   io = __shfl_xor(bi, m, 64);
                if (vo < v || (vo == v && io < bi)) { v = vo; bi = io; }
            }
            if (lane == 0) { wminv[r0 + r][wave] = v; wmini[r0 + r][wave] = bi; }
        }
        __syncthreads();
        if (t < 8) {
            float v = wminv[r0 + t][0]; int bi = wmini[r0 + t][0];
            for (int w = 1; w < 4; ++w) {
                const float vo = wminv[r0 + t][w]; const int io = wmini[r0 + t][w];
                if (vo < v || (vo == v && io < bi)) { v = vo; bi = io; }
            }
            rowmin[r0 + t] = v;
            out[CODE_OFF + (base + r0 + t) * 3 + level] = (float)bi;
        }
        __syncthreads();

        // ---- phase 3: e = exp(dmin - d) in place, row sums via shuffle ----
#pragma unroll
        for (int r = 0; r < 8; ++r) {
            const float mn = rowmin[r0 + r];
            float4 A = acc[r];
            A.x = expf(__fsub_rn(mn, A.x));
            A.y = expf(__fsub_rn(mn, A.y));
            A.z = expf(__fsub_rn(mn, A.z));
            A.w = expf(__fsub_rn(mn, A.w));
            acc[r] = A;
            float s = (A.x + A.y) + (A.z + A.w);
#pragma unroll
            for (int m = 1; m < 64; m <<= 1) s += __shfl_xor(s, m, 64);
            if (lane == 0) wsum[r0 + r][wave] = s;
        }
        __syncthreads();
        if (t < 8) {
            const float L = (wsum[r0 + t][0] + wsum[r0 + t][1])
                          + (wsum[r0 + t][2] + wsum[r0 + t][3]);
            rcpL[r0 + t] = 1.0f / L;
        }
        __syncthreads();

        // ---- phase 4 partial: accumulate avg_probs contributions in registers ----
#pragma unroll
        for (int r = 0; r < 8; ++r) {
            const float rl = rcpL[r0 + r];
            s0 = fmaf(acc[r].x, rl, s0);
            s1 = fmaf(acc[r].y, rl, s1);
            s2 = fmaf(acc[r].z, rl, s2);
            s3 = fmaf(acc[r].w, rl, s3);
        }
    }

    // ---- commit partial: d at argmin == ||r - q||^2 (loss tolerance loose) ----
    if (t == 64) {
        double cs = 0.0;
        for (int r = 0; r < 16; ++r) cs += (double)rowmin[r];
        atomicAdd(&commit[level], cs);
    }

    // ---- avg_probs atomics: one per code per block ----
    atomicAdd(&avgp[level * KCODES + c + 0], s0);
    atomicAdd(&avgp[level * KCODES + c + 1], s1);
    atomicAdd(&avgp[level * KCODES + c + 2], s2);
    atomicAdd(&avgp[level * KCODES + c + 3], s3);
}

__global__ __launch_bounds__(256) void finalize_kernel(const float* __restrict__ avgp,
                                                       const double* __restrict__ commit,
                                                       float* __restrict__ out) {
    __shared__ double red[256];
    __shared__ float  kls[3];
    const int t = threadIdx.x;
    for (int l = 0; l < 3; ++l) {
        double p = 0.0;
        for (int k = t; k < KCODES; k += 256) {
            const float avg = avgp[l * KCODES + k] * (1.0f / 131072.0f);
            p += (double)avg * log((double)avg * 1024.0 + 1e-8);
        }
        red[t] = p; __syncthreads();
        for (int off = 128; off >= 1; off >>= 1) {
            if (t < off) red[t] += red[t + off];
            __syncthreads();
        }
        if (t == 0) kls[l] = (float)red[0];
        __syncthreads();
    }
    if (t == 0) {
        float cv = 0.f, u = 0.f;
        for (int l = 0; l < 3; ++l) {
            const float m = (float)(commit[l] * (1.0 / 16777216.0));
            cv = __fadd_rn(cv, m);                      // + mean((sg(r)-q)^2)
            cv = __fadd_rn(cv, __fmul_rn(0.25f, m));    // + BETA * mean((r-sg(q))^2)
            u = __fadd_rn(u, __fmul_rn(1e-3f, kls[l]));
        }
        out[SCAL_OFF]     = cv;
        out[SCAL_OFF + 1] = u;
    }
}

__global__ __launch_bounds__(256) void gather_kernel(const float* __restrict__ W,
                                                     float* __restrict__ out) {
    const size_t g = (size_t)blockIdx.x * 256 + threadIdx.x;   // f4 index
    const size_t n = g >> 5;
    const int f = (int)(g & 31);
    const float* codes = out + CODE_OFF + n * 3;
    const int c0 = (int)codes[0], c1 = (int)codes[1], c2 = (int)codes[2];
    const float4 a = *(const float4*)(W + (size_t)c0 * DIMS + 4 * f);
    const float4 b = *(const float4*)(W + (size_t)(KCODES + c1) * DIMS + 4 * f);
    const float4 c = *(const float4*)(W + (size_t)(2 * KCODES + c2) * DIMS + 4 * f);
    float4 o;   // ((q1 + q2) + q3), fp32 like reference
    o.x = __fadd_rn(__fadd_rn(a.x, b.x), c.x);
    o.y = __fadd_rn(__fadd_rn(a.y, b.y), c.y);
    o.z = __fadd_rn(__fadd_rn(a.z, b.z), c.z);
    o.w = __fadd_rn(__fadd_rn(a.w, b.w), c.w);
    *(float4*)(out + n * DIMS + 4 * f) = o;
}

extern "C" void kernel_launch(void* const* d_in, const int* in_sizes, int n_in,
                              void* d_out, int out_size, void* d_ws, size_t ws_size,
                              hipStream_t stream) {
    const float* x = (const float*)d_in[0];
    const float* W = (const float*)d_in[1];
    float* out = (float*)d_out;
    float*  avgp   = (float*)d_ws;
    double* commit = (double*)((char*)d_ws + WS_COMMIT_OFF);
    float*  wkp    = (float*)((char*)d_ws + WS_WK_OFF);
    float*  WT     = (float*)((char*)d_ws + WS_WT_OFF);

    hipLaunchKernelGGL(init_acc, dim3(1), dim3(256), 0, stream, avgp, commit);
    hipLaunchKernelGGL(wnorm_kernel, dim3(768), dim3(256), 0, stream, W, wkp);
    hipLaunchKernelGGL(transpose_w, dim3(16, 4, 3), dim3(256), 0, stream, W, WT);
    for (int l = 0; l < NLEV; ++l)
        hipLaunchKernelGGL(rvq_level, dim3(NROWS / 16), dim3(256), 0, stream,
                           x, W, WT, wkp, out, avgp, commit, l);
    hipLaunchKernelGGL(finalize_kernel, dim3(1), dim3(256), 0, stream, avgp, commit, out);
    hipLaunchKernelGGL(gather_kernel, dim3((NROWS * 32) / 256), dim3(256), 0, stream, W, out);
}